// Round 1
// baseline (367.078 us; speedup 1.0000x reference)
//
#include <hip/hip_runtime.h>

// HEALPix pad, p=1, n=128, C=128, B12=24 (B=2 x 12 faces), fp32.
// out[b12, c, r, col] (130x130) from in[b12, c, 128, 128] + neighbor-face halos.

#define NPLANE_OUT 16900   // 130*130
#define QUADS 4225         // 16900/4

__device__ __forceinline__ float hp_face(const float* __restrict__ in, size_t baseoff,
                                         int q, int i, int j) {
  // face q plane: offset baseoff + q*128ch*16384 ; (i,j) within 128x128
  return in[baseoff + ((size_t)q << 21) + (i << 7) + j];
}

__device__ __forceinline__ float hp_val(const float* __restrict__ in, size_t baseoff,
                                        int type, int m, int face, int r, int col) {
  // interior fast check
  if ((unsigned)(r - 1) < 128u && (unsigned)(col - 1) < 128u)
    return hp_face(in, baseoff, face, r - 1, col - 1);

  const int L = 127;
  if (r == 0) {
    if (col == 0) {  // TL corner
      if (type == 0) return hp_face(in, baseoff, (m + 2) & 3, 0, 0);
      if (type == 1) return 0.5f * (hp_face(in, baseoff, m, L, 0) +
                                    hp_face(in, baseoff, (m + 3) & 3, 0, L));
      return hp_face(in, baseoff, m, L, L);
    }
    if (col == 129) {  // TR corner
      if (type == 0) return hp_face(in, baseoff, (m + 1) & 3, L, 0);
      if (type == 1) return hp_face(in, baseoff, 4 + ((m + 1) & 3), L, 0);
      return hp_face(in, baseoff, 8 + ((m + 1) & 3), L, 0);
    }
    int j = col - 1;  // top row
    if (type == 0) return hp_face(in, baseoff, (m + 1) & 3, j, 0);
    if (type == 1) return hp_face(in, baseoff, m, L, j);
    return hp_face(in, baseoff, 4 + ((m + 1) & 3), L, j);
  }
  if (r == 129) {
    if (col == 0) {  // BL corner
      if (type == 0) return hp_face(in, baseoff, (m + 3) & 3, 0, L);
      if (type == 1) return hp_face(in, baseoff, 4 + ((m + 3) & 3), 0, L);
      return hp_face(in, baseoff, 8 + ((m + 3) & 3), 0, L);
    }
    if (col == 129) {  // BR corner
      if (type == 0) return hp_face(in, baseoff, 8 + m, 0, 0);
      if (type == 1) return 0.5f * (hp_face(in, baseoff, 8 + ((m + 3) & 3), 0, L) +
                                    hp_face(in, baseoff, 8 + m, L, 0));
      return hp_face(in, baseoff, 8 + ((m + 2) & 3), L, L);
    }
    int j = col - 1;  // bottom row
    if (type == 0) return hp_face(in, baseoff, 4 + m, 0, j);
    if (type == 1) return hp_face(in, baseoff, 8 + ((m + 3) & 3), 0, j);
    return hp_face(in, baseoff, 8 + ((m + 3) & 3), j, L);
  }
  int i = r - 1;
  if (col == 0) {  // left column
    if (type == 0) return hp_face(in, baseoff, (m + 3) & 3, 0, i);
    if (type == 1) return hp_face(in, baseoff, (m + 3) & 3, i, L);
    return hp_face(in, baseoff, 4 + m, i, L);
  }
  // col == 129, right column
  if (type == 0) return hp_face(in, baseoff, 4 + ((m + 1) & 3), i, 0);
  if (type == 1) return hp_face(in, baseoff, 8 + m, i, 0);
  return hp_face(in, baseoff, 8 + ((m + 1) & 3), L, i);
}

__global__ __launch_bounds__(256) void CREDITHEALPix_90975997264316_kernel(
    const float* __restrict__ in, float* __restrict__ out) {
  int q = blockIdx.x * 256 + threadIdx.x;  // quad index within plane
  if (q >= QUADS) return;
  int plane = blockIdx.y;      // 0..3071 : b12*128 + c
  int b12 = plane >> 7;
  int c = plane & 127;
  int batch = (b12 >= 12) ? 1 : 0;
  int face = b12 - batch * 12;
  int type = face >> 2;        // 0=north, 1=equatorial, 2=south
  int m = face & 3;
  // per-(batch,channel) base offset into input: ((batch*12)*128 + c) * 16384
  size_t baseoff = (((size_t)batch * 12 * 128) + (size_t)c) << 14;

  int flat0 = q * 4;
  unsigned r0 = (unsigned)flat0 / 130u;
  unsigned c0 = (unsigned)flat0 - r0 * 130u;

  float4 v;
  if (r0 >= 1u && r0 <= 128u && c0 >= 1u && c0 <= 125u) {
    // fully interior quad, same row: 4 coalesced scalar loads
    const float* src = in + baseoff + ((size_t)face << 21) +
                       ((size_t)(r0 - 1) << 7) + (c0 - 1);
    v.x = src[0]; v.y = src[1]; v.z = src[2]; v.w = src[3];
  } else {
    float tmp[4];
#pragma unroll
    for (int k = 0; k < 4; ++k) {
      int flat = flat0 + k;
      unsigned r = (unsigned)flat / 130u;
      unsigned col = (unsigned)flat - r * 130u;
      tmp[k] = hp_val(in, baseoff, type, m, face, (int)r, (int)col);
    }
    v.x = tmp[0]; v.y = tmp[1]; v.z = tmp[2]; v.w = tmp[3];
  }
  *(float4*)(out + (size_t)plane * NPLANE_OUT + flat0) = v;
}

extern "C" void kernel_launch(void* const* d_in, const int* in_sizes, int n_in,
                              void* d_out, int out_size, void* d_ws, size_t ws_size,
                              hipStream_t stream) {
  const float* in = (const float*)d_in[0];
  float* out = (float*)d_out;
  // planes = 24*128 = 3072 ; quads per plane = 4225 -> 17 blocks of 256
  dim3 grid(17, 3072, 1);
  dim3 block(256, 1, 1);
  CREDITHEALPix_90975997264316_kernel<<<grid, block, 0, stream>>>(in, out);
}

// Round 2
// 361.412 us; speedup vs baseline: 1.0157x; 1.0157x over previous
//
#include <hip/hip_runtime.h>

// HEALPix pad, p=1, n=128, C=128, B12=24 (B=2 x 12 faces), fp32.
// out[b12, c, r, col] (130x130) from in[b12, c, 128, 128] + neighbor-face halos.
// R2: split bulk interior copy (input-aligned float4, divergence-free) from
// border fill (1 block/plane, 516 elems).

#define NPLANE_OUT 16900   // 130*130

__device__ __forceinline__ float hp_face(const float* __restrict__ in, size_t baseoff,
                                         int q, int i, int j) {
  return in[baseoff + ((size_t)q << 21) + (i << 7) + j];
}

__device__ __forceinline__ float hp_val(const float* __restrict__ in, size_t baseoff,
                                        int type, int m, int face, int r, int col) {
  const int L = 127;
  if (r == 0) {
    if (col == 0) {  // TL corner
      if (type == 0) return hp_face(in, baseoff, (m + 2) & 3, 0, 0);
      if (type == 1) return 0.5f * (hp_face(in, baseoff, m, L, 0) +
                                    hp_face(in, baseoff, (m + 3) & 3, 0, L));
      return hp_face(in, baseoff, m, L, L);
    }
    if (col == 129) {  // TR corner
      if (type == 0) return hp_face(in, baseoff, (m + 1) & 3, L, 0);
      if (type == 1) return hp_face(in, baseoff, 4 + ((m + 1) & 3), L, 0);
      return hp_face(in, baseoff, 8 + ((m + 1) & 3), L, 0);
    }
    int j = col - 1;  // top row
    if (type == 0) return hp_face(in, baseoff, (m + 1) & 3, j, 0);
    if (type == 1) return hp_face(in, baseoff, m, L, j);
    return hp_face(in, baseoff, 4 + ((m + 1) & 3), L, j);
  }
  if (r == 129) {
    if (col == 0) {  // BL corner
      if (type == 0) return hp_face(in, baseoff, (m + 3) & 3, 0, L);
      if (type == 1) return hp_face(in, baseoff, 4 + ((m + 3) & 3), 0, L);
      return hp_face(in, baseoff, 8 + ((m + 3) & 3), 0, L);
    }
    if (col == 129) {  // BR corner
      if (type == 0) return hp_face(in, baseoff, 8 + m, 0, 0);
      if (type == 1) return 0.5f * (hp_face(in, baseoff, 8 + ((m + 3) & 3), 0, L) +
                                    hp_face(in, baseoff, 8 + m, L, 0));
      return hp_face(in, baseoff, 8 + ((m + 2) & 3), L, L);
    }
    int j = col - 1;  // bottom row
    if (type == 0) return hp_face(in, baseoff, 4 + m, 0, j);
    if (type == 1) return hp_face(in, baseoff, 8 + ((m + 3) & 3), 0, j);
    return hp_face(in, baseoff, 8 + ((m + 3) & 3), j, L);
  }
  int i = r - 1;
  if (col == 0) {  // left column
    if (type == 0) return hp_face(in, baseoff, (m + 3) & 3, 0, i);
    if (type == 1) return hp_face(in, baseoff, (m + 3) & 3, i, L);
    return hp_face(in, baseoff, 4 + m, i, L);
  }
  // col == 129, right column
  if (type == 0) return hp_face(in, baseoff, 4 + ((m + 1) & 3), i, 0);
  if (type == 1) return hp_face(in, baseoff, 8 + m, i, 0);
  return hp_face(in, baseoff, 8 + ((m + 1) & 3), L, i);
}

typedef float f4v __attribute__((ext_vector_type(4)));

__global__ __launch_bounds__(256) void CREDITHEALPix_90975997264316_kernel(
    const float* __restrict__ in, float* __restrict__ out) {
  int plane = blockIdx.y;      // 0..3071 : b12*128 + c
  int b12 = plane >> 7;
  int c = plane & 127;
  int batch = (b12 >= 12) ? 1 : 0;
  int face = b12 - batch * 12;
  int type = face >> 2;        // 0=north, 1=equatorial, 2=south
  int m = face & 3;
  size_t baseoff = (((size_t)batch * 1536) + (size_t)c) << 14;  // (batch*12*128+c)*16384
  size_t face_off = baseoff + ((size_t)face << 21);
  float* __restrict__ oplane = out + (size_t)plane * NPLANE_OUT;

  if (blockIdx.x < 16) {
    // ---- interior bulk copy: input-aligned, zero divergence ----
    int iq = blockIdx.x * 256 + threadIdx.x;  // 0..4095 input quads
    int r = iq >> 5;                          // input row 0..127
    int j4 = (iq & 31) << 2;                  // input col 0,4,...,124
    f4v v = *(const f4v*)(in + face_off + ((size_t)r << 7) + j4);
    // output (r+1, j4+1..j4+4): contiguous, 4B-aligned 16B store
    __builtin_memcpy(oplane + (r + 1) * 130 + 1 + j4, &v, 16);
  } else {
    // ---- border: 516 elements per plane ----
    for (int e = threadIdx.x; e < 516; e += 256) {
      int r, col;
      if (e < 130)      { r = 0;       col = e; }
      else if (e < 260) { r = 129;     col = e - 130; }
      else if (e < 388) { r = e - 259; col = 0; }        // rows 1..128, left
      else              { r = e - 387; col = 129; }      // rows 1..128, right
      oplane[r * 130 + col] = hp_val(in, baseoff, type, m, face, r, col);
    }
  }
}

extern "C" void kernel_launch(void* const* d_in, const int* in_sizes, int n_in,
                              void* d_out, int out_size, void* d_ws, size_t ws_size,
                              hipStream_t stream) {
  const float* in = (const float*)d_in[0];
  float* out = (float*)d_out;
  // grid.x: 16 interior blocks (4096 quads) + 1 border block, per plane
  dim3 grid(17, 3072, 1);
  dim3 block(256, 1, 1);
  CREDITHEALPix_90975997264316_kernel<<<grid, block, 0, stream>>>(in, out);
}